// Round 4
// baseline (335.855 us; speedup 1.0000x reference)
//
#include <hip/hip_runtime.h>

// 3D trilinear grid_sample (border, align_corners=False) of (4,256,256,256) f32
// voxels at N points, + bias. Output (N,4) f32.
//
// R4: z-slab binning (128 bins = 2 z-planes), bins pinned to XCDs via
// blockIdx%8; sample from the ORIGINAL f32 table with a ~3 MB L2-resident
// window per XCD. Fixes R3's dropped points: border bin z0=0 carries 1.5x
// interior mass (clamp) -> cap raised to 24576, and any overflow point is
// sampled DIRECTLY in the bin pass (correctness independent of cap).

#define SIDE 256
#define CHAN_STRIDE ((size_t)SIDE * SIDE * SIDE)
#define NBINS 128          // bin = z0 >> 1
#define CNT_STRIDE 16      // ints -> 64 B per counter
#define CNT_BYTES (NBINS * CNT_STRIDE * 4)
#define PPT 8              // points per thread in bin pass
#define CAP 24576          // border bin mean 19531 (+36 sigma); overflow safe anyway

typedef float f2_unal __attribute__((ext_vector_type(2), aligned(4)));

// ---------------- shared sampling math (verbatim from R1, passed) ----------
__device__ __forceinline__ float4 sample_one(
    float px, float py, float pz,
    const float* __restrict__ vox, float4 bias)
{
    float ix = fminf(fmaxf(fmaf(px, 128.0f, 127.5f), 0.0f), 255.0f);
    float iy = fminf(fmaxf(fmaf(py, 128.0f, 127.5f), 0.0f), 255.0f);
    float iz = fminf(fmaxf(fmaf(pz, 128.0f, 127.5f), 0.0f), 255.0f);

    float fx = floorf(ix), fy = floorf(iy), fz = floorf(iz);
    float wx = ix - fx, wy = iy - fy, wz = iz - fz;
    int x0 = (int)fx, y0 = (int)fy, z0 = (int)fz;

    int xb = min(x0, SIDE - 2);
    bool xhi = (x0 > xb);
    int y1 = min(y0 + 1, SIDE - 1);
    int z1 = min(z0 + 1, SIDE - 1);

    float ux = 1.0f - wx, uy = 1.0f - wy, uz = 1.0f - wz;
    float w00 = uz * uy, w01 = uz * wy, w10 = wz * uy, w11 = wz * wy;

    size_t b00 = ((size_t)(z0 * SIDE + y0)) * SIDE + xb;
    size_t b01 = ((size_t)(z0 * SIDE + y1)) * SIDE + xb;
    size_t b10 = ((size_t)(z1 * SIDE + y0)) * SIDE + xb;
    size_t b11 = ((size_t)(z1 * SIDE + y1)) * SIDE + xb;

    float r[4];
#pragma unroll
    for (int c = 0; c < 4; ++c) {
        const float* v = vox + (size_t)c * CHAN_STRIDE;
        f2_unal q00 = *(const f2_unal*)(v + b00);
        f2_unal q01 = *(const f2_unal*)(v + b01);
        f2_unal q10 = *(const f2_unal*)(v + b10);
        f2_unal q11 = *(const f2_unal*)(v + b11);
        float a00 = xhi ? q00.y : q00.x;
        float a01 = xhi ? q01.y : q01.x;
        float a10 = xhi ? q10.y : q10.x;
        float a11 = xhi ? q11.y : q11.x;
        r[c] = w00 * fmaf(a00, ux, q00.y * wx)
             + w01 * fmaf(a01, ux, q01.y * wx)
             + w10 * fmaf(a10, ux, q10.y * wx)
             + w11 * fmaf(a11, ux, q11.y * wx);
    }
    return make_float4(r[0] + bias.x, r[1] + bias.y, r[2] + bias.z, r[3] + bias.w);
}

// ---------------- pass 1: bin points by z-slab -----------------------------
__global__ __launch_bounds__(256) void bin_kernel(
    const float* __restrict__ pos, int n,
    int* __restrict__ gcnt, uint4* __restrict__ recs,
    const float* __restrict__ vox, const float* __restrict__ biasp,
    float4* __restrict__ out)
{
    __shared__ int hist[NBINS];
    __shared__ int base[NBINS];
    int tid = threadIdx.x;
    for (int b = tid; b < NBINS; b += 256) hist[b] = 0;
    __syncthreads();

    size_t start = ((size_t)blockIdx.x * 256 + tid) * PPT;
    float buf[3 * PPT];
    bool full = (start + PPT <= (size_t)n);
    if (full) {
        const float4* p4 = (const float4*)(pos + 3 * start);  // 96 B, 16B aligned
#pragma unroll
        for (int k = 0; k < 3 * PPT / 4; ++k) ((float4*)buf)[k] = p4[k];
    } else {
#pragma unroll
        for (int k = 0; k < 3 * PPT; ++k) {
            size_t e = 3 * start + k;
            buf[k] = (e < 3 * (size_t)n) ? pos[e] : 0.0f;
        }
    }

    int bin[PPT], rank[PPT];
#pragma unroll
    for (int j = 0; j < PPT; ++j) {
        if (start + j < (size_t)n) {
            float pz = buf[3 * j + 2];
            float izf = fminf(fmaxf(fmaf(pz, 128.0f, 127.5f), 0.0f), 255.0f);
            int z0 = (int)floorf(izf);
            bin[j] = z0 >> 1;
            rank[j] = atomicAdd(&hist[bin[j]], 1);
        } else bin[j] = -1;
    }
    __syncthreads();
    for (int b = tid; b < NBINS; b += 256)
        base[b] = hist[b] ? atomicAdd(&gcnt[b * CNT_STRIDE], hist[b]) : 0;
    __syncthreads();

    float4 bias = *(const float4*)biasp;
#pragma unroll
    for (int j = 0; j < PPT; ++j) {
        if (bin[j] < 0) continue;
        int slot = base[bin[j]] + rank[j];
        if (slot < CAP) {
            uint4 r;
            r.x = __float_as_uint(buf[3 * j + 0]);
            r.y = __float_as_uint(buf[3 * j + 1]);
            r.z = __float_as_uint(buf[3 * j + 2]);
            r.w = (unsigned)(start + j);
            recs[(size_t)bin[j] * CAP + slot] = r;
        } else {
            // overflow: sample directly -- no point can ever be dropped
            out[start + j] = sample_one(buf[3 * j + 0], buf[3 * j + 1],
                                        buf[3 * j + 2], vox, bias);
        }
    }
}

// ---------------- pass 2: sample in bin order, XCD-pinned ------------------
__global__ __launch_bounds__(256) void sample_binned_kernel(
    const uint4* __restrict__ recs, const int* __restrict__ gcnt,
    const float* __restrict__ vox, const float* __restrict__ biasp,
    float4* __restrict__ out)
{
    float4 bias = *(const float4*)biasp;
    int tid = threadIdx.x;
    int xcd = blockIdx.x & 7;          // round-robin block->XCD
    int blk = blockIdx.x >> 3;
    int stride = (gridDim.x >> 3) * 256;
    const int BPB = NBINS / 8;         // 16 z-contiguous bins per XCD
    for (int b = xcd * BPB; b < (xcd + 1) * BPB; ++b) {
        int cnt = min(gcnt[b * CNT_STRIDE], CAP);
        const uint4* rec = recs + (size_t)b * CAP;
        for (int r = blk * 256 + tid; r < cnt; r += stride) {
            uint4 R = rec[r];
            out[R.w] = sample_one(__uint_as_float(R.x), __uint_as_float(R.y),
                                  __uint_as_float(R.z), vox, bias);
        }
    }
}

// ---------------- fallback: direct (R1, 636 us) ----------------------------
__global__ __launch_bounds__(256) void vox_trilerp_kernel(
    const float* __restrict__ pos, const float* __restrict__ vox,
    const float* __restrict__ biasp, float* __restrict__ out, int n)
{
    int i = blockIdx.x * blockDim.x + threadIdx.x;
    if (i >= n) return;
    float4 bias = *(const float4*)biasp;
    float4 res = sample_one(pos[3 * (size_t)i], pos[3 * (size_t)i + 1],
                            pos[3 * (size_t)i + 2], vox, bias);
    *(float4*)(out + 4 * (size_t)i) = res;
}

extern "C" void kernel_launch(void* const* d_in, const int* in_sizes, int n_in,
                              void* d_out, int out_size, void* d_ws, size_t ws_size,
                              hipStream_t stream) {
    const float* pos  = (const float*)d_in[0];
    const float* vox  = (const float*)d_in[1];
    const float* bias = (const float*)d_in[2];
    float* out = (float*)d_out;

    int n = in_sizes[0] / 3;
    size_t need = (size_t)CNT_BYTES + (size_t)NBINS * CAP * sizeof(uint4); // 50.3 MB

    if (ws_size >= need && n >= 256 * PPT) {
        int* gcnt = (int*)d_ws;
        uint4* recs = (uint4*)((char*)d_ws + CNT_BYTES);
        hipMemsetAsync(d_ws, 0, CNT_BYTES, stream);
        int grid1 = (n + 256 * PPT - 1) / (256 * PPT);
        bin_kernel<<<grid1, 256, 0, stream>>>(pos, n, gcnt, recs, vox, bias,
                                              (float4*)out);
        sample_binned_kernel<<<2048, 256, 0, stream>>>(recs, gcnt, vox, bias,
                                                       (float4*)out);
    } else {
        int grid = (n + 255) / 256;
        vox_trilerp_kernel<<<grid, 256, 0, stream>>>(pos, vox, bias, out, n);
    }
}

// Round 5
// 334.169 us; speedup vs baseline: 1.0050x; 1.0050x over previous
//
#include <hip/hip_runtime.h>

// 3D trilinear grid_sample (border, align_corners=False) of (4,256,256,256) f32
// voxels at N points, + bias. Output (N,4) f32.
//
// R5: z-slab binning (128 bins = 2 z-planes = 2 MB f32 window), bins pinned to
// XCDs (blockIdx&7), sample from ORIGINAL f32 table. R4 post-mortem: binning
// raised L2 reuse (2.1GB -> 775MB fetch) but the schedule wasted it (2 launch
// generations + 3/4 dead blocks). Fix: 1024 blocks (4096 waves, single
// co-resident generation), group=128 blocks -> 32768 threads/XCD-group matches
// bin count (~15.6K-24K), so every thread does <=1 point/bin, no dead blocks,
// groups walk z-windows in near-lockstep.

#define SIDE 256
#define CHAN_STRIDE ((size_t)SIDE * SIDE * SIDE)
#define NBINS 128          // bin = z0 >> 1
#define CNT_STRIDE 16      // ints -> 64 B per counter
#define CNT_BYTES (NBINS * CNT_STRIDE * 4)
#define PPT 8              // points per thread in bin pass
#define CAP 24576          // border bin mean 19531; overflow handled anyway

typedef float f2_unal __attribute__((ext_vector_type(2), aligned(4)));

// ---------------- shared sampling math (verbatim from R1, passed) ----------
__device__ __forceinline__ float4 sample_one(
    float px, float py, float pz,
    const float* __restrict__ vox, float4 bias)
{
    float ix = fminf(fmaxf(fmaf(px, 128.0f, 127.5f), 0.0f), 255.0f);
    float iy = fminf(fmaxf(fmaf(py, 128.0f, 127.5f), 0.0f), 255.0f);
    float iz = fminf(fmaxf(fmaf(pz, 128.0f, 127.5f), 0.0f), 255.0f);

    float fx = floorf(ix), fy = floorf(iy), fz = floorf(iz);
    float wx = ix - fx, wy = iy - fy, wz = iz - fz;
    int x0 = (int)fx, y0 = (int)fy, z0 = (int)fz;

    int xb = min(x0, SIDE - 2);
    bool xhi = (x0 > xb);
    int y1 = min(y0 + 1, SIDE - 1);
    int z1 = min(z0 + 1, SIDE - 1);

    float ux = 1.0f - wx, uy = 1.0f - wy, uz = 1.0f - wz;
    float w00 = uz * uy, w01 = uz * wy, w10 = wz * uy, w11 = wz * wy;

    size_t b00 = ((size_t)(z0 * SIDE + y0)) * SIDE + xb;
    size_t b01 = ((size_t)(z0 * SIDE + y1)) * SIDE + xb;
    size_t b10 = ((size_t)(z1 * SIDE + y0)) * SIDE + xb;
    size_t b11 = ((size_t)(z1 * SIDE + y1)) * SIDE + xb;

    float r[4];
#pragma unroll
    for (int c = 0; c < 4; ++c) {
        const float* v = vox + (size_t)c * CHAN_STRIDE;
        f2_unal q00 = *(const f2_unal*)(v + b00);
        f2_unal q01 = *(const f2_unal*)(v + b01);
        f2_unal q10 = *(const f2_unal*)(v + b10);
        f2_unal q11 = *(const f2_unal*)(v + b11);
        float a00 = xhi ? q00.y : q00.x;
        float a01 = xhi ? q01.y : q01.x;
        float a10 = xhi ? q10.y : q10.x;
        float a11 = xhi ? q11.y : q11.x;
        r[c] = w00 * fmaf(a00, ux, q00.y * wx)
             + w01 * fmaf(a01, ux, q01.y * wx)
             + w10 * fmaf(a10, ux, q10.y * wx)
             + w11 * fmaf(a11, ux, q11.y * wx);
    }
    return make_float4(r[0] + bias.x, r[1] + bias.y, r[2] + bias.z, r[3] + bias.w);
}

// ---------------- pass 1: bin points by z-slab -----------------------------
__global__ __launch_bounds__(256) void bin_kernel(
    const float* __restrict__ pos, int n,
    int* __restrict__ gcnt, uint4* __restrict__ recs,
    const float* __restrict__ vox, const float* __restrict__ biasp,
    float4* __restrict__ out)
{
    __shared__ int hist[NBINS];
    __shared__ int base[NBINS];
    int tid = threadIdx.x;
    for (int b = tid; b < NBINS; b += 256) hist[b] = 0;
    __syncthreads();

    size_t start = ((size_t)blockIdx.x * 256 + tid) * PPT;
    float buf[3 * PPT];
    bool full = (start + PPT <= (size_t)n);
    if (full) {
        const float4* p4 = (const float4*)(pos + 3 * start);  // 96 B, 16B aligned
#pragma unroll
        for (int k = 0; k < 3 * PPT / 4; ++k) ((float4*)buf)[k] = p4[k];
    } else {
#pragma unroll
        for (int k = 0; k < 3 * PPT; ++k) {
            size_t e = 3 * start + k;
            buf[k] = (e < 3 * (size_t)n) ? pos[e] : 0.0f;
        }
    }

    int bin[PPT], rank[PPT];
#pragma unroll
    for (int j = 0; j < PPT; ++j) {
        if (start + j < (size_t)n) {
            float pz = buf[3 * j + 2];
            float izf = fminf(fmaxf(fmaf(pz, 128.0f, 127.5f), 0.0f), 255.0f);
            int z0 = (int)floorf(izf);
            bin[j] = z0 >> 1;
            rank[j] = atomicAdd(&hist[bin[j]], 1);
        } else bin[j] = -1;
    }
    __syncthreads();
    for (int b = tid; b < NBINS; b += 256)
        base[b] = hist[b] ? atomicAdd(&gcnt[b * CNT_STRIDE], hist[b]) : 0;
    __syncthreads();

    float4 bias = *(const float4*)biasp;
#pragma unroll
    for (int j = 0; j < PPT; ++j) {
        if (bin[j] < 0) continue;
        int slot = base[bin[j]] + rank[j];
        if (slot < CAP) {
            uint4 r;
            r.x = __float_as_uint(buf[3 * j + 0]);
            r.y = __float_as_uint(buf[3 * j + 1]);
            r.z = __float_as_uint(buf[3 * j + 2]);
            r.w = (unsigned)(start + j);
            recs[(size_t)bin[j] * CAP + slot] = r;
        } else {
            // overflow: sample directly -- no point can ever be dropped
            out[start + j] = sample_one(buf[3 * j + 0], buf[3 * j + 1],
                                        buf[3 * j + 2], vox, bias);
        }
    }
}

// ---------------- pass 2: sample in bin order, XCD-pinned ------------------
// 1024 blocks x 256 thr = 4096 waves (half machine) -> one co-resident
// generation. Group = gridDim/8 = 128 blocks -> 32768 threads walk each bin
// (cnt <= CAP 24576) with <=1 point/thread, near-lockstep z-window.
__global__ __launch_bounds__(256) void sample_binned_kernel(
    const uint4* __restrict__ recs, const int* __restrict__ gcnt,
    const float* __restrict__ vox, const float* __restrict__ biasp,
    float4* __restrict__ out)
{
    float4 bias = *(const float4*)biasp;
    int tid = threadIdx.x;
    int xcd = blockIdx.x & 7;          // round-robin block->XCD
    int blk = blockIdx.x >> 3;
    int stride = (gridDim.x >> 3) * 256;
    const int BPB = NBINS / 8;         // 16 z-contiguous bins per XCD
    for (int b = xcd * BPB; b < (xcd + 1) * BPB; ++b) {
        int cnt = min(gcnt[b * CNT_STRIDE], CAP);
        const uint4* rec = recs + (size_t)b * CAP;
        for (int r = blk * 256 + tid; r < cnt; r += stride) {
            uint4 R = rec[r];
            out[R.w] = sample_one(__uint_as_float(R.x), __uint_as_float(R.y),
                                  __uint_as_float(R.z), vox, bias);
        }
    }
}

// ---------------- fallback: direct (R1, 636 us) ----------------------------
__global__ __launch_bounds__(256) void vox_trilerp_kernel(
    const float* __restrict__ pos, const float* __restrict__ vox,
    const float* __restrict__ biasp, float* __restrict__ out, int n)
{
    int i = blockIdx.x * blockDim.x + threadIdx.x;
    if (i >= n) return;
    float4 bias = *(const float4*)biasp;
    float4 res = sample_one(pos[3 * (size_t)i], pos[3 * (size_t)i + 1],
                            pos[3 * (size_t)i + 2], vox, bias);
    *(float4*)(out + 4 * (size_t)i) = res;
}

extern "C" void kernel_launch(void* const* d_in, const int* in_sizes, int n_in,
                              void* d_out, int out_size, void* d_ws, size_t ws_size,
                              hipStream_t stream) {
    const float* pos  = (const float*)d_in[0];
    const float* vox  = (const float*)d_in[1];
    const float* bias = (const float*)d_in[2];
    float* out = (float*)d_out;

    int n = in_sizes[0] / 3;
    size_t need = (size_t)CNT_BYTES + (size_t)NBINS * CAP * sizeof(uint4); // 50.3 MB

    if (ws_size >= need && n >= 256 * PPT) {
        int* gcnt = (int*)d_ws;
        uint4* recs = (uint4*)((char*)d_ws + CNT_BYTES);
        hipMemsetAsync(d_ws, 0, CNT_BYTES, stream);
        int grid1 = (n + 256 * PPT - 1) / (256 * PPT);
        bin_kernel<<<grid1, 256, 0, stream>>>(pos, n, gcnt, recs, vox, bias,
                                              (float4*)out);
        sample_binned_kernel<<<1024, 256, 0, stream>>>(recs, gcnt, vox, bias,
                                                       (float4*)out);
    } else {
        int grid = (n + 255) / 256;
        vox_trilerp_kernel<<<grid, 256, 0, stream>>>(pos, vox, bias, out, n);
    }
}

// Round 6
// 172.238 us; speedup vs baseline: 1.9500x; 1.9402x over previous
//
#include <hip/hip_runtime.h>

// 3D trilinear grid_sample (border, align_corners=False) of (4,256,256,256) f32
// voxels at N points, + bias. Output (N,4) f32.
//
// R6: tile-and-stage. Bin points into 37x37 (z,y) tiles (7 planes/rows each).
// Sample kernel: 1 block per tile, stages the tile's (8 z-planes x 8 y-rows x
// 256 x x 4 ch) sub-volume COALESCED from the f32 table into a 128 KiB fp16
// LDS tile, then samples all the tile's points from LDS. Table is read as
// pure streaming (350 MB total, halo amp (8/7)^2) instead of scattered 64B
// lines -- R1-R5 showed the cache path is stuck at 2.3-3.5 TB/s scatter rate
// with >=2.8x compulsory traffic. Overflow-proof binning from R4.

#define SIDE 256
#define CHAN_STRIDE ((size_t)SIDE * SIDE * SIDE)
#define ZR 7
#define YR 7
#define NT 37                       // ceil(256/7)
#define NTILES (NT * NT)            // 1369
#define CNT_STRIDE 16               // ints -> 64 B per counter
#define CNT_BYTES (NTILES * CNT_STRIDE * 4)
#define PPT 8                       // points per thread in bin pass
#define CAP 3072                    // mean pts/tile ~1500 (border ~1740); overflow safe

typedef float f2_unal __attribute__((ext_vector_type(2), aligned(4)));
typedef _Float16 h8_lds __attribute__((ext_vector_type(8), aligned(8)));
typedef _Float16 h8_al  __attribute__((ext_vector_type(8), aligned(16)));

// ---------------- f32 global sampling (R1, proven) -------------------------
__device__ __forceinline__ float4 sample_one(
    float px, float py, float pz,
    const float* __restrict__ vox, float4 bias)
{
    float ix = fminf(fmaxf(fmaf(px, 128.0f, 127.5f), 0.0f), 255.0f);
    float iy = fminf(fmaxf(fmaf(py, 128.0f, 127.5f), 0.0f), 255.0f);
    float iz = fminf(fmaxf(fmaf(pz, 128.0f, 127.5f), 0.0f), 255.0f);
    float fx = floorf(ix), fy = floorf(iy), fz = floorf(iz);
    float wx = ix - fx, wy = iy - fy, wz = iz - fz;
    int x0 = (int)fx, y0 = (int)fy, z0 = (int)fz;
    int xb = min(x0, SIDE - 2);
    bool xhi = (x0 > xb);
    int y1 = min(y0 + 1, SIDE - 1);
    int z1 = min(z0 + 1, SIDE - 1);
    float ux = 1.0f - wx, uy = 1.0f - wy, uz = 1.0f - wz;
    float w00 = uz * uy, w01 = uz * wy, w10 = wz * uy, w11 = wz * wy;
    size_t b00 = ((size_t)(z0 * SIDE + y0)) * SIDE + xb;
    size_t b01 = ((size_t)(z0 * SIDE + y1)) * SIDE + xb;
    size_t b10 = ((size_t)(z1 * SIDE + y0)) * SIDE + xb;
    size_t b11 = ((size_t)(z1 * SIDE + y1)) * SIDE + xb;
    float r[4];
#pragma unroll
    for (int c = 0; c < 4; ++c) {
        const float* v = vox + (size_t)c * CHAN_STRIDE;
        f2_unal q00 = *(const f2_unal*)(v + b00);
        f2_unal q01 = *(const f2_unal*)(v + b01);
        f2_unal q10 = *(const f2_unal*)(v + b10);
        f2_unal q11 = *(const f2_unal*)(v + b11);
        float a00 = xhi ? q00.y : q00.x;
        float a01 = xhi ? q01.y : q01.x;
        float a10 = xhi ? q10.y : q10.x;
        float a11 = xhi ? q11.y : q11.x;
        r[c] = w00 * fmaf(a00, ux, q00.y * wx)
             + w01 * fmaf(a01, ux, q01.y * wx)
             + w10 * fmaf(a10, ux, q10.y * wx)
             + w11 * fmaf(a11, ux, q11.y * wx);
    }
    return make_float4(r[0] + bias.x, r[1] + bias.y, r[2] + bias.z, r[3] + bias.w);
}

// ---------------- pass 1: bin points by (z,y) tile -------------------------
__global__ __launch_bounds__(256) void bin_kernel(
    const float* __restrict__ pos, int n,
    int* __restrict__ gcnt, uint4* __restrict__ recs,
    const float* __restrict__ vox, const float* __restrict__ biasp,
    float4* __restrict__ out)
{
    __shared__ int hist[NTILES];
    __shared__ int base[NTILES];
    int tid = threadIdx.x;
    for (int b = tid; b < NTILES; b += 256) hist[b] = 0;
    __syncthreads();

    size_t start = ((size_t)blockIdx.x * 256 + tid) * PPT;
    float buf[3 * PPT];
    bool full = (start + PPT <= (size_t)n);
    if (full) {
        const float4* p4 = (const float4*)(pos + 3 * start);  // 96B, 16B-aligned
#pragma unroll
        for (int k = 0; k < 3 * PPT / 4; ++k) ((float4*)buf)[k] = p4[k];
    } else {
#pragma unroll
        for (int k = 0; k < 3 * PPT; ++k) {
            size_t e = 3 * start + k;
            buf[k] = (e < 3 * (size_t)n) ? pos[e] : 0.0f;
        }
    }

    int bin[PPT], rank[PPT];
#pragma unroll
    for (int j = 0; j < PPT; ++j) {
        if (start + j < (size_t)n) {
            float py = buf[3 * j + 1];
            float pz = buf[3 * j + 2];
            float iyf = fminf(fmaxf(fmaf(py, 128.0f, 127.5f), 0.0f), 255.0f);
            float izf = fminf(fmaxf(fmaf(pz, 128.0f, 127.5f), 0.0f), 255.0f);
            int y0 = (int)floorf(iyf);
            int z0 = (int)floorf(izf);
            bin[j] = (z0 / ZR) * NT + (y0 / YR);
            rank[j] = atomicAdd(&hist[bin[j]], 1);
        } else bin[j] = -1;
    }
    __syncthreads();
    for (int b = tid; b < NTILES; b += 256)
        base[b] = hist[b] ? atomicAdd(&gcnt[b * CNT_STRIDE], hist[b]) : 0;
    __syncthreads();

    float4 bias = *(const float4*)biasp;
#pragma unroll
    for (int j = 0; j < PPT; ++j) {
        if (bin[j] < 0) continue;
        int slot = base[bin[j]] + rank[j];
        if (slot < CAP) {
            uint4 r;
            r.x = __float_as_uint(buf[3 * j + 0]);
            r.y = __float_as_uint(buf[3 * j + 1]);
            r.z = __float_as_uint(buf[3 * j + 2]);
            r.w = (unsigned)(start + j);
            recs[(size_t)bin[j] * CAP + slot] = r;
        } else {
            // overflow: sample directly from global f32 -- no point dropped
            out[start + j] = sample_one(buf[3 * j + 0], buf[3 * j + 1],
                                        buf[3 * j + 2], vox, bias);
        }
    }
}

// ---------------- pass 2: stage tile in LDS, sample from LDS ---------------
// LDS tile: 8 planes x 8 rows x 256 x x 4 ch, fp16 interleaved (x,c) = 128 KiB.
__global__ __launch_bounds__(1024) void sample_tiles_kernel(
    const uint4* __restrict__ recs, const int* __restrict__ gcnt,
    const float* __restrict__ vox, const float* __restrict__ biasp,
    float4* __restrict__ out)
{
    __shared__ _Float16 tile[8 * 8 * 256 * 4];  // 128 KiB

    float4 bias = *(const float4*)biasp;
    int tid = threadIdx.x;

    for (int t = blockIdx.x; t < NTILES; t += gridDim.x) {
        int zt = t / NT, yt = t - zt * NT;
        int zbase = zt * ZR, ybase = yt * YR;

        // ---- stage: 64 (plane,row) combos x 128 x-pairs; 8 iters/thread ----
#pragma unroll
        for (int it = 0; it < 8; ++it) {
            int q = it * 1024 + tid;        // 0..8191
            int p = q & 127;                // x-pair index (x = 2p, 2p+1)
            int rowp = q >> 7;              // 0..63
            int r = rowp & 7, pl = rowp >> 3;
            int zp = min(zbase + pl, SIDE - 1);
            int yp = min(ybase + r, SIDE - 1);
            size_t gbase = ((size_t)(zp * SIDE + yp)) * SIDE + p * 2;
            float2 f0 = *(const float2*)(vox + gbase);
            float2 f1 = *(const float2*)(vox + CHAN_STRIDE + gbase);
            float2 f2 = *(const float2*)(vox + 2 * CHAN_STRIDE + gbase);
            float2 f3 = *(const float2*)(vox + 3 * CHAN_STRIDE + gbase);
            h8_al o;
            o[0] = (_Float16)f0.x; o[1] = (_Float16)f1.x;
            o[2] = (_Float16)f2.x; o[3] = (_Float16)f3.x;
            o[4] = (_Float16)f0.y; o[5] = (_Float16)f1.y;
            o[6] = (_Float16)f2.y; o[7] = (_Float16)f3.y;
            *(h8_al*)(tile + ((size_t)rowp * 256 + p * 2) * 4) = o;  // 16B-aligned
        }
        __syncthreads();

        // ---- sample this tile's points from LDS ----
        int cnt = min(gcnt[t * CNT_STRIDE], CAP);
        const uint4* rec = recs + (size_t)t * CAP;
        for (int r = tid; r < cnt; r += 1024) {
            uint4 R = rec[r];
            float px = __uint_as_float(R.x);
            float py = __uint_as_float(R.y);
            float pz = __uint_as_float(R.z);

            float ix = fminf(fmaxf(fmaf(px, 128.0f, 127.5f), 0.0f), 255.0f);
            float iy = fminf(fmaxf(fmaf(py, 128.0f, 127.5f), 0.0f), 255.0f);
            float iz = fminf(fmaxf(fmaf(pz, 128.0f, 127.5f), 0.0f), 255.0f);
            float fx = floorf(ix), fy = floorf(iy), fz = floorf(iz);
            float wx = ix - fx, wy = iy - fy, wz = iz - fz;
            int x0 = (int)fx, y0 = (int)fy, z0 = (int)fz;
            int xb = min(x0, SIDE - 2);
            bool xhi = (x0 > xb);
            int y1 = min(y0 + 1, SIDE - 1);
            int z1 = min(z0 + 1, SIDE - 1);

            int zl = z0 - zbase, zl1 = z1 - zbase;   // 0..7, staged
            int yl = y0 - ybase, yl1 = y1 - ybase;   // 0..7, staged

            float ux = 1.0f - wx, uy = 1.0f - wy, uz = 1.0f - wz;
            float w00 = uz * uy, w01 = uz * wy, w10 = wz * uy, w11 = wz * wy;

            h8_lds v00 = *(const h8_lds*)(tile + ((zl  * 8 + yl ) * 256 + xb) * 4);
            h8_lds v01 = *(const h8_lds*)(tile + ((zl  * 8 + yl1) * 256 + xb) * 4);
            h8_lds v10 = *(const h8_lds*)(tile + ((zl1 * 8 + yl ) * 256 + xb) * 4);
            h8_lds v11 = *(const h8_lds*)(tile + ((zl1 * 8 + yl1) * 256 + xb) * 4);

            float acc[4];
#pragma unroll
            for (int c = 0; c < 4; ++c) {
                float lo00 = (float)(xhi ? v00[4 + c] : v00[c]);
                float lo01 = (float)(xhi ? v01[4 + c] : v01[c]);
                float lo10 = (float)(xhi ? v10[4 + c] : v10[c]);
                float lo11 = (float)(xhi ? v11[4 + c] : v11[c]);
                float hi00 = (float)v00[4 + c];
                float hi01 = (float)v01[4 + c];
                float hi10 = (float)v10[4 + c];
                float hi11 = (float)v11[4 + c];
                acc[c] = w00 * fmaf(lo00, ux, hi00 * wx)
                       + w01 * fmaf(lo01, ux, hi01 * wx)
                       + w10 * fmaf(lo10, ux, hi10 * wx)
                       + w11 * fmaf(lo11, ux, hi11 * wx);
            }
            out[R.w] = make_float4(acc[0] + bias.x, acc[1] + bias.y,
                                   acc[2] + bias.z, acc[3] + bias.w);
        }
        __syncthreads();  // protect tile before next stage
    }
}

// ---------------- fallback: direct (R1, 636 us) ----------------------------
__global__ __launch_bounds__(256) void vox_trilerp_kernel(
    const float* __restrict__ pos, const float* __restrict__ vox,
    const float* __restrict__ biasp, float* __restrict__ out, int n)
{
    int i = blockIdx.x * blockDim.x + threadIdx.x;
    if (i >= n) return;
    float4 bias = *(const float4*)biasp;
    float4 res = sample_one(pos[3 * (size_t)i], pos[3 * (size_t)i + 1],
                            pos[3 * (size_t)i + 2], vox, bias);
    *(float4*)(out + 4 * (size_t)i) = res;
}

extern "C" void kernel_launch(void* const* d_in, const int* in_sizes, int n_in,
                              void* d_out, int out_size, void* d_ws, size_t ws_size,
                              hipStream_t stream) {
    const float* pos  = (const float*)d_in[0];
    const float* vox  = (const float*)d_in[1];
    const float* bias = (const float*)d_in[2];
    float* out = (float*)d_out;

    int n = in_sizes[0] / 3;
    size_t need = (size_t)CNT_BYTES + (size_t)NTILES * CAP * sizeof(uint4); // ~67.4 MB

    if (ws_size >= need && n >= 256 * PPT) {
        int* gcnt = (int*)d_ws;
        uint4* recs = (uint4*)((char*)d_ws + CNT_BYTES);
        hipMemsetAsync(d_ws, 0, CNT_BYTES, stream);
        int grid1 = (n + 256 * PPT - 1) / (256 * PPT);
        bin_kernel<<<grid1, 256, 0, stream>>>(pos, n, gcnt, recs, vox, bias,
                                              (float4*)out);
        sample_tiles_kernel<<<NTILES, 1024, 0, stream>>>(recs, gcnt, vox, bias,
                                                         (float4*)out);
    } else {
        int grid = (n + 255) / 256;
        vox_trilerp_kernel<<<grid, 256, 0, stream>>>(pos, vox, bias, out, n);
    }
}